// Round 1
// baseline (650.822 us; speedup 1.0000x reference)
//
#include <hip/hip_runtime.h>
#include <hip/hip_bf16.h>
#include <math.h>

#define N_EDGES_C 320000
#define N_PART 10000
#define EMBED 256
#define NRBF 16
#define OUTE 512

typedef __attribute__((ext_vector_type(8))) short short8;
typedef __attribute__((ext_vector_type(4))) float float4v;

// ---------------- workspace layout (bytes; all 16-aligned) ----------------
#define WS_SUMMED   0            // 10000*256*2  = 5,120,000   bf16
#define WS_BUF0     6000000      // 10000*512*2  = 10,240,000  bf16
#define WS_BUF1     17000000     // 10,240,000                  bf16
#define WS_WTUP     28000000     // 512*256*2 = 262,144         bf16 [N][K]
#define WS_WTD0     28300000     // 512*512*2 = 524,288
#define WS_WTD1     28900000     // 524,288
#define WS_CNT      29500000     // 10000*4
#define WS_CUR      29540000     // 10000*4  (contiguous with CNT for one memset)
#define WS_OFF      29580000     // 10000*4
#define WS_ELIST    29640000     // 320000*4

// ---------------------------------------------------------------------------
// CSR build: histogram -> single-block scan (1024 thr) -> fill
// ---------------------------------------------------------------------------
__global__ __launch_bounds__(256) void hist_kernel(
    const int* __restrict__ idx_i, int* __restrict__ cnt)
{
    int e = blockIdx.x * 256 + threadIdx.x;
    if (e < N_EDGES_C) atomicAdd(&cnt[idx_i[e]], 1);
}

__global__ __launch_bounds__(1024) void scan_kernel(
    const int* __restrict__ cnt, int* __restrict__ off)
{
    __shared__ int s[1024];
    const int t = threadIdx.x;
    const int base = t * 10;                 // 1024*10 >= 10000
    int v[10];
    int loc = 0;
#pragma unroll
    for (int i = 0; i < 10; ++i) {
        int idx = base + i;
        int c = (idx < N_PART) ? cnt[idx] : 0;
        v[i] = c;
        loc += c;
    }
    s[t] = loc;
    __syncthreads();
    for (int d = 1; d < 1024; d <<= 1) {
        int x = (t >= d) ? s[t - d] : 0;
        __syncthreads();
        s[t] += x;
        __syncthreads();
    }
    int pre = (t > 0) ? s[t - 1] : 0;        // exclusive prefix of thread sums
#pragma unroll
    for (int i = 0; i < 10; ++i) {
        int idx = base + i;
        if (idx < N_PART) off[idx] = pre;
        pre += v[i];
    }
}

__global__ __launch_bounds__(256) void fill_kernel(
    const int* __restrict__ idx_i, const int* __restrict__ off,
    int* __restrict__ cur, int* __restrict__ elist)
{
    int e = blockIdx.x * 256 + threadIdx.x;
    if (e >= N_EDGES_C) return;
    int p = idx_i[e];
    int pos = atomicAdd(&cur[p], 1);
    elist[off[p] + pos] = e;
}

// ---------------------------------------------------------------------------
// Gather v3: wave-per-edge, lane-per-4-columns.
//   - W_rbf columns for this lane live in 16 float4 REGISTERS (no LDS reads
//     in the inner loop at all; previous version issued up to 64 ds_read_b32
//     per edge at ~5.8 cyc each on the per-CU shared LDS pipe).
//   - messages row read as one dwordx4 per lane (1 KB/wave, coalesced);
//     rbf row read as 4 broadcast float4 loads per WAVE (was per-thread x4
//     waves = 16 instrs/edge).
//   - elist value prefetched one iteration ahead to break the serial
//     elist -> {rbf,messages} chain.
//   - 4 waves stride the edge list; one LDS reduction + barrier at the end.
// ---------------------------------------------------------------------------
__global__ __launch_bounds__(256) void gather_kernel(
    const float* __restrict__ messages, const float* __restrict__ rbf,
    const float* __restrict__ W_rbf, const int* __restrict__ off,
    const int* __restrict__ cnt, const int* __restrict__ elist,
    __hip_bfloat16* __restrict__ summed)
{
    __shared__ float red[4][EMBED];          // 4 KB
    const int tid  = threadIdx.x;
    const int wave = tid >> 6;
    const int lane = tid & 63;
    const int c4   = lane << 2;              // column base 0..252
    const int p    = blockIdx.x;

    // W_rbf[k][c4..c4+3] for k=0..15 -> 16 float4 in registers (64 VGPRs).
    // All indices compile-time constant so these never spill to scratch.
    float4v wr[16];
#pragma unroll
    for (int k = 0; k < 16; ++k)
        wr[k] = *(const float4v*)(W_rbf + k * EMBED + c4);

    const int base = off[p];
    const int deg  = cnt[p];

    float4v acc = {0.f, 0.f, 0.f, 0.f};

    int j = wave;
    int e_next = (j < deg) ? elist[base + j] : 0;
    for (; j < deg; j += 4) {
        const int e = e_next;
        if (j + 4 < deg) e_next = elist[base + j + 4];   // prefetch next edge id
        const float4v* r4 = (const float4v*)(rbf + (size_t)e * NRBF);
        const float4v r0 = r4[0], r1 = r4[1], r2 = r4[2], r3 = r4[3];
        const float4v m  = *(const float4v*)(messages + (size_t)e * EMBED + c4);
        float4v t = {0.f, 0.f, 0.f, 0.f};
#define GATE(rv, comp, kk)                                   \
        t[0] = fmaf(rv[comp], wr[kk][0], t[0]);              \
        t[1] = fmaf(rv[comp], wr[kk][1], t[1]);              \
        t[2] = fmaf(rv[comp], wr[kk][2], t[2]);              \
        t[3] = fmaf(rv[comp], wr[kk][3], t[3]);
        GATE(r0, 0, 0)  GATE(r0, 1, 1)  GATE(r0, 2, 2)  GATE(r0, 3, 3)
        GATE(r1, 0, 4)  GATE(r1, 1, 5)  GATE(r1, 2, 6)  GATE(r1, 3, 7)
        GATE(r2, 0, 8)  GATE(r2, 1, 9)  GATE(r2, 2, 10) GATE(r2, 3, 11)
        GATE(r3, 0, 12) GATE(r3, 1, 13) GATE(r3, 2, 14) GATE(r3, 3, 15)
#undef GATE
        acc[0] = fmaf(m[0], t[0], acc[0]);
        acc[1] = fmaf(m[1], t[1], acc[1]);
        acc[2] = fmaf(m[2], t[2], acc[2]);
        acc[3] = fmaf(m[3], t[3], acc[3]);
    }

    *(float4v*)&red[wave][c4] = acc;
    __syncthreads();
    const float s = red[0][tid] + red[1][tid] + red[2][tid] + red[3][tid];
    summed[(size_t)p * EMBED + tid] = __float2bfloat16(s);
}

// ---------------------------------------------------------------------------
// Weight transpose+convert, all three weights in one launch (z = which).
// Wt[n][k] = bf16(W[k][n]).
// ---------------------------------------------------------------------------
__global__ __launch_bounds__(256) void transpose_cvt_all(
    const float* __restrict__ W_up, const float* __restrict__ W_d0,
    const float* __restrict__ W_d1, __hip_bfloat16* __restrict__ wt_up,
    __hip_bfloat16* __restrict__ wt_d0, __hip_bfloat16* __restrict__ wt_d1)
{
    const int z = blockIdx.z;
    const float* W = (z == 0) ? W_up : (z == 1) ? W_d0 : W_d1;
    __hip_bfloat16* Wt = (z == 0) ? wt_up : (z == 1) ? wt_d0 : wt_d1;
    const int K = (z == 0) ? EMBED : OUTE;
    const int N = OUTE;
    if (blockIdx.y * 32 >= K) return;

    __shared__ float t[32][33];
    const int bn = blockIdx.x * 32;
    const int bk = blockIdx.y * 32;
    const int x = threadIdx.x & 31;
    const int y8 = threadIdx.x >> 5;
#pragma unroll
    for (int yy = y8; yy < 32; yy += 8)
        t[yy][x] = W[(size_t)(bk + yy) * N + bn + x];
    __syncthreads();
#pragma unroll
    for (int yy = y8; yy < 32; yy += 8)
        Wt[(size_t)(bn + yy) * K + bk + x] = __float2bfloat16(t[x][yy]);
}

// ---------------------------------------------------------------------------
// bf16 MFMA GEMM: 128x128 tile, BK=32, 4 waves, 4x4 mfma_f32_16x16x32_bf16
// per wave. FUSE=1: don't store C; instead out[row] += swish(v) * Wf[col]
// (shfl-reduce over the 16-lane row group, one fp32 atomicAdd per row).
// ---------------------------------------------------------------------------
#define BM 128
#define BN 128
#define BK 32
#define LDSP 40

template <int ACT, int FUSE>
__global__ __launch_bounds__(256) void gemm_mfma(
    const __hip_bfloat16* __restrict__ A,   // [M][K]
    const __hip_bfloat16* __restrict__ Bt,  // [N][K]
    const float* __restrict__ bias,          // [N] or null
    __hip_bfloat16* __restrict__ C,          // [M][N]   (FUSE=0)
    const float* __restrict__ Wf,            // [N]      (FUSE=1)
    float* __restrict__ out,                 // [M]      (FUSE=1)
    int M, int K, int N)
{
    __shared__ short As[BM * LDSP];
    __shared__ short Bs[BN * LDSP];

    const int tid  = threadIdx.x;
    const int bm   = blockIdx.x * BM;
    const int bn   = blockIdx.y * BN;
    const int wave = tid >> 6;
    const int lane = tid & 63;
    const int wm   = (wave >> 1) * 64;
    const int wn   = (wave & 1) * 64;
    const int l16  = lane & 15;
    const int quad = lane >> 4;

    float4v acc[4][4];
#pragma unroll
    for (int i = 0; i < 4; ++i)
#pragma unroll
        for (int j = 0; j < 4; ++j)
#pragma unroll
            for (int r = 0; r < 4; ++r) acc[i][j][r] = 0.f;

    const int sr = tid >> 1;         // staging row 0..127
    const int sh = (tid & 1) * 16;   // staging k-offset 0 / 16

    for (int k0 = 0; k0 < K; k0 += BK) {
        short8 av0, av1;
        if (bm + sr < M) {
            const short8* ga = (const short8*)((const short*)A + (size_t)(bm + sr) * K + k0 + sh);
            av0 = ga[0];
            av1 = ga[1];
        } else {
#pragma unroll
            for (int i = 0; i < 8; ++i) { av0[i] = 0; av1[i] = 0; }
        }
        *(short8*)&As[sr * LDSP + sh]     = av0;
        *(short8*)&As[sr * LDSP + sh + 8] = av1;
        const short8* gb = (const short8*)((const short*)Bt + (size_t)(bn + sr) * K + k0 + sh);
        short8 bv0 = gb[0], bv1 = gb[1];
        *(short8*)&Bs[sr * LDSP + sh]     = bv0;
        *(short8*)&Bs[sr * LDSP + sh + 8] = bv1;
        __syncthreads();

        short8 af[4], bf[4];
#pragma unroll
        for (int mt = 0; mt < 4; ++mt)
            af[mt] = *(const short8*)&As[(wm + mt * 16 + l16) * LDSP + quad * 8];
#pragma unroll
        for (int nt = 0; nt < 4; ++nt)
            bf[nt] = *(const short8*)&Bs[(wn + nt * 16 + l16) * LDSP + quad * 8];
#pragma unroll
        for (int mt = 0; mt < 4; ++mt)
#pragma unroll
            for (int nt = 0; nt < 4; ++nt)
                acc[mt][nt] = __builtin_amdgcn_mfma_f32_16x16x32_bf16(
                    af[mt], bf[nt], acc[mt][nt], 0, 0, 0);
        __syncthreads();
    }

    if (!FUSE) {
#pragma unroll
        for (int mt = 0; mt < 4; ++mt) {
            const int row0 = bm + wm + mt * 16 + quad * 4;
#pragma unroll
            for (int nt = 0; nt < 4; ++nt) {
                const int col = bn + wn + nt * 16 + l16;
                const float bv = bias ? bias[col] : 0.f;
#pragma unroll
                for (int r = 0; r < 4; ++r) {
                    const int rr = row0 + r;
                    if (rr < M) {
                        float v = acc[mt][nt][r] + bv;
                        if (ACT == 1) v = v / (1.f + expf(-v));
                        C[(size_t)rr * N + col] = __float2bfloat16(v);
                    }
                }
            }
        }
    } else {
        float bv[4], wfv[4];
#pragma unroll
        for (int nt = 0; nt < 4; ++nt) {
            const int col = bn + wn + nt * 16 + l16;
            bv[nt]  = bias ? bias[col] : 0.f;
            wfv[nt] = Wf[col];
        }
#pragma unroll
        for (int mt = 0; mt < 4; ++mt) {
#pragma unroll
            for (int r = 0; r < 4; ++r) {
                const int row = bm + wm + mt * 16 + quad * 4 + r;
                float s = 0.f;
#pragma unroll
                for (int nt = 0; nt < 4; ++nt) {
                    float v = acc[mt][nt][r] + bv[nt];
                    if (ACT == 1) v = v / (1.f + expf(-v));
                    s = fmaf(v, wfv[nt], s);
                }
#pragma unroll
                for (int o = 8; o > 0; o >>= 1) s += __shfl_down(s, o);
                if (l16 == 0 && row < M) atomicAdd(&out[row], s);
            }
        }
    }
}

extern "C" void kernel_launch(void* const* d_in, const int* in_sizes, int n_in,
                              void* d_out, int out_size, void* d_ws, size_t ws_size,
                              hipStream_t stream) {
    const float* messages = (const float*)d_in[0];
    const float* rbf      = (const float*)d_in[1];
    const int*   idx_i    = (const int*)d_in[2];
    const float* W_rbf    = (const float*)d_in[3];
    const float* W_up     = (const float*)d_in[4];
    const float* W_d0     = (const float*)d_in[5];
    const float* b_d0     = (const float*)d_in[6];
    const float* W_d1     = (const float*)d_in[7];
    const float* b_d1     = (const float*)d_in[8];
    const float* W_final  = (const float*)d_in[9];
    float* out = (float*)d_out;

    char* ws = (char*)d_ws;
    __hip_bfloat16* summed = (__hip_bfloat16*)(ws + WS_SUMMED);
    __hip_bfloat16* buf0   = (__hip_bfloat16*)(ws + WS_BUF0);
    __hip_bfloat16* buf1   = (__hip_bfloat16*)(ws + WS_BUF1);
    __hip_bfloat16* wt_up  = (__hip_bfloat16*)(ws + WS_WTUP);
    __hip_bfloat16* wt_d0  = (__hip_bfloat16*)(ws + WS_WTD0);
    __hip_bfloat16* wt_d1  = (__hip_bfloat16*)(ws + WS_WTD1);
    int* cnt   = (int*)(ws + WS_CNT);
    int* cur   = (int*)(ws + WS_CUR);
    int* offp  = (int*)(ws + WS_OFF);
    int* elist = (int*)(ws + WS_ELIST);

    hipMemsetAsync(ws + WS_CNT, 0, 80000, stream);                 // cnt+cur
    hipMemsetAsync(d_out, 0, (size_t)N_PART * sizeof(float), stream);

    // CSR build
    hist_kernel<<<(N_EDGES_C + 255) / 256, 256, 0, stream>>>(idx_i, cnt);
    scan_kernel<<<1, 1024, 0, stream>>>(cnt, offp);
    fill_kernel<<<(N_EDGES_C + 255) / 256, 256, 0, stream>>>(idx_i, offp, cur, elist);

    // weight transpose+convert (one launch for all three)
    transpose_cvt_all<<<dim3(OUTE / 32, OUTE / 32, 3), 256, 0, stream>>>(
        W_up, W_d0, W_d1, wt_up, wt_d0, wt_d1);

    // gather (no atomics)
    gather_kernel<<<N_PART, 256, 0, stream>>>(messages, rbf, W_rbf, offp, cnt,
                                              elist, summed);

    // MLP via bf16 MFMA GEMMs; layer 3 fuses the W_final dot
    dim3 g((N_PART + BM - 1) / BM, OUTE / BN);  // 79 x 4
    gemm_mfma<0, 0><<<g, 256, 0, stream>>>(summed, wt_up, nullptr, buf0,
                                           nullptr, nullptr, N_PART, EMBED, OUTE);
    gemm_mfma<1, 0><<<g, 256, 0, stream>>>(buf0, wt_d0, b_d0, buf1,
                                           nullptr, nullptr, N_PART, OUTE, OUTE);
    gemm_mfma<1, 1><<<g, 256, 0, stream>>>(buf1, wt_d1, b_d1, nullptr,
                                           W_final, out, N_PART, OUTE, OUTE);
}

// Round 2
// 628.342 us; speedup vs baseline: 1.0358x; 1.0358x over previous
//
#include <hip/hip_runtime.h>
#include <hip/hip_bf16.h>
#include <math.h>

#define N_EDGES_C 320000
#define N_PART 10000
#define EMBED 256
#define NRBF 16
#define OUTE 512

typedef __attribute__((ext_vector_type(8))) short short8;
typedef __attribute__((ext_vector_type(4))) short short4v;
typedef __attribute__((ext_vector_type(4))) float float4v;

__device__ __forceinline__ short bfbits(float x) {
    __hip_bfloat16 h = __float2bfloat16(x);
    return *(short*)&h;
}

// ---------------- workspace layout (bytes; all 16-aligned) ----------------
#define WS_SUMMED   0            // 10000*256*2  = 5,120,000   bf16
#define WS_BUF0     6000000      // 10000*512*2  = 10,240,000  bf16
#define WS_BUF1     17000000     // 10,240,000                  bf16
#define WS_WTUP     28000000     // 512*256*2 = 262,144         bf16 [N][K]
#define WS_WTD0     28300000     // 512*512*2 = 524,288
#define WS_WTD1     28900000     // 524,288
#define WS_CNT      29500000     // 10000*4
#define WS_CUR      29540000     // 10000*4  (contiguous with CNT for one memset)
#define WS_OFF      29580000     // 10000*4
#define WS_ELIST    29640000     // 320000*4 = 1,280,000
#define WS_WRT      30920000     // 256*64*2 = 32,768  (W_rbf^T bf16 hi/lo packed, K=64)
#define WS_SUMF     30960000     // 10000*256*4 = 10,240,000  f32 scatter target

// ---------------------------------------------------------------------------
// CSR build: histogram -> single-block scan (1024 thr) -> fill
// ---------------------------------------------------------------------------
__global__ __launch_bounds__(256) void hist_kernel(
    const int* __restrict__ idx_i, int* __restrict__ cnt)
{
    int e = blockIdx.x * 256 + threadIdx.x;
    if (e < N_EDGES_C) atomicAdd(&cnt[idx_i[e]], 1);
}

__global__ __launch_bounds__(1024) void scan_kernel(
    const int* __restrict__ cnt, int* __restrict__ off)
{
    __shared__ int s[1024];
    const int t = threadIdx.x;
    const int base = t * 10;                 // 1024*10 >= 10000
    int v[10];
    int loc = 0;
#pragma unroll
    for (int i = 0; i < 10; ++i) {
        int idx = base + i;
        int c = (idx < N_PART) ? cnt[idx] : 0;
        v[i] = c;
        loc += c;
    }
    s[t] = loc;
    __syncthreads();
    for (int d = 1; d < 1024; d <<= 1) {
        int x = (t >= d) ? s[t - d] : 0;
        __syncthreads();
        s[t] += x;
        __syncthreads();
    }
    int pre = (t > 0) ? s[t - 1] : 0;        // exclusive prefix of thread sums
#pragma unroll
    for (int i = 0; i < 10; ++i) {
        int idx = base + i;
        if (idx < N_PART) off[idx] = pre;
        pre += v[i];
    }
}

__global__ __launch_bounds__(256) void fill_kernel(
    const int* __restrict__ idx_i, const int* __restrict__ off,
    int* __restrict__ cur, int* __restrict__ elist)
{
    int e = blockIdx.x * 256 + threadIdx.x;
    if (e >= N_EDGES_C) return;
    int p = idx_i[e];
    int pos = atomicAdd(&cur[p], 1);
    elist[off[p] + pos] = e;
}

// ---------------------------------------------------------------------------
// prep_wrbf: build wrt[n][k] bf16, [256 cols][K=64]:
//   k  0..15 : hi(W_rbf[k][n])
//   k 16..31 : hi(W_rbf[k][n])     (pairs with A's x_lo half)
//   k 32..47 : lo(W_rbf[k][n])     (pairs with A's x_hi half)
//   k 48..63 : 0
// With A = [x_hi | x_lo | x_hi | 0] the MFMA computes
//   x_hi*w_hi + x_lo*w_hi + x_hi*w_lo  =  x*w - x_lo*w_lo  (error ~1e-5).
// ---------------------------------------------------------------------------
__global__ __launch_bounds__(256) void prep_wrbf(
    const float* __restrict__ W_rbf, __hip_bfloat16* __restrict__ wrt)
{
    const int n = threadIdx.x;
    short row[64];
#pragma unroll
    for (int k = 0; k < 16; ++k) {
        const float w = W_rbf[k * EMBED + n];
        const short h = bfbits(w);
        __hip_bfloat16 hb = *(__hip_bfloat16*)&h;
        const short l = bfbits(w - __bfloat162float(hb));
        row[k] = h; row[16 + k] = h; row[32 + k] = l; row[48 + k] = 0;
    }
    short* dst = (short*)wrt + n * 64;
#pragma unroll
    for (int g = 0; g < 8; ++g) {
        short8 v;
#pragma unroll
        for (int i = 0; i < 8; ++i) v[i] = row[g * 8 + i];
        *(short8*)(dst + g * 8) = v;
    }
}

// ---------------------------------------------------------------------------
// Gather v4 (MFMA gate): one block per 32-edge CSR chunk.
//   phase 0: el/pid into LDS
//   phase 1: rbf rows -> bf16 hi/lo A-tile [32][64] in LDS;
//            P[32][256] = A @ wrt via 16 mfma_f32_16x16x32_bf16 per wave
//            (gate moves off the VALU: was ~71 us of vector FMA).
//   phase 2: thread-per-column; acc += messages[e][c]*P[j][c] over the chunk,
//            flushing to f32 summed at particle-run boundaries (CSR order
//            makes runs contiguous; boundary particles handled by atomicAdd).
// LDS = 4.6K(A) + 33.3K(P) + 0.25K = 38.4 KB -> 4 blocks/CU = 16 waves.
// ---------------------------------------------------------------------------
#define CHUNK 32
#define ASTR 72          // A LDS stride in shorts (64 + 8 pad)
#define PSTR 260         // P LDS stride in floats (quad rows land 16 banks apart)

__global__ __launch_bounds__(256) void gather_mfma(
    const float* __restrict__ messages, const float* __restrict__ rbf,
    const int* __restrict__ idx_i, const int* __restrict__ elist,
    const __hip_bfloat16* __restrict__ wrt,
    float* __restrict__ sumf)
{
    __shared__ short A[CHUNK * ASTR];
    __shared__ float P[CHUNK * PSTR];
    __shared__ int el[CHUNK];
    __shared__ int pid[CHUNK];

    const int tid  = threadIdx.x;
    const int wave = tid >> 6;
    const int lane = tid & 63;
    const int l16  = lane & 15;
    const int quad = lane >> 4;
    const int base = blockIdx.x * CHUNK;   // 320000/32 = 10000 chunks exactly

    // b-frags from global wrt (16 KB hot in L2): wave w owns n-tiles 4w..4w+3.
    short8 bfr[4][2];
#pragma unroll
    for (int i = 0; i < 4; ++i) {
        const int col = (wave * 4 + i) * 16 + l16;
#pragma unroll
        for (int s = 0; s < 2; ++s)
            bfr[i][s] = *(const short8*)((const short*)wrt + col * 64 + s * 32 + quad * 8);
    }

    if (tid < CHUNK) {
        const int e = elist[base + tid];
        el[tid] = e;
        pid[tid] = idx_i[e];
    }
    __syncthreads();

    // A staging: threads 0..127; j = t>>2, k-quad = (t&3)*4
    if (tid < 128) {
        const int j  = tid >> 2;
        const int kq = (tid & 3) << 2;
        const float4v r = *(const float4v*)(rbf + (size_t)el[j] * NRBF + kq);
        short4v hi, lo;
#pragma unroll
        for (int i = 0; i < 4; ++i) {
            const short h = bfbits(r[i]);
            __hip_bfloat16 hb = *(__hip_bfloat16*)&h;
            hi[i] = h;
            lo[i] = bfbits(r[i] - __bfloat162float(hb));
        }
        *(short4v*)&A[j * ASTR + kq]      = hi;
        *(short4v*)&A[j * ASTR + 16 + kq] = lo;
        *(short4v*)&A[j * ASTR + 32 + kq] = hi;
        *(short4v*)&A[j * ASTR + 48 + kq] = (short4v){0, 0, 0, 0};
    }
    __syncthreads();

    // MFMA: 2 m-tiles x 4 n-tiles x 2 k-steps per wave
    float4v acc[2][4];
#pragma unroll
    for (int mt = 0; mt < 2; ++mt)
#pragma unroll
        for (int i = 0; i < 4; ++i)
#pragma unroll
            for (int r = 0; r < 4; ++r) acc[mt][i][r] = 0.f;

    short8 af[2][2];
#pragma unroll
    for (int mt = 0; mt < 2; ++mt)
#pragma unroll
        for (int s = 0; s < 2; ++s)
            af[mt][s] = *(const short8*)&A[(mt * 16 + l16) * ASTR + s * 32 + quad * 8];
#pragma unroll
    for (int mt = 0; mt < 2; ++mt)
#pragma unroll
        for (int i = 0; i < 4; ++i) {
            acc[mt][i] = __builtin_amdgcn_mfma_f32_16x16x32_bf16(af[mt][0], bfr[i][0], acc[mt][i], 0, 0, 0);
            acc[mt][i] = __builtin_amdgcn_mfma_f32_16x16x32_bf16(af[mt][1], bfr[i][1], acc[mt][i], 0, 0, 0);
        }
    // C layout (verified m89): col = lane&15, row = (lane>>4)*4 + r
#pragma unroll
    for (int mt = 0; mt < 2; ++mt)
#pragma unroll
        for (int i = 0; i < 4; ++i) {
            const int col  = (wave * 4 + i) * 16 + l16;
            const int row0 = mt * 16 + quad * 4;
#pragma unroll
            for (int r = 0; r < 4; ++r)
                P[(row0 + r) * PSTR + col] = acc[mt][i][r];
        }
    __syncthreads();

    // phase 2: thread c = tid; two half-chunks of 16 to bound VGPR for mv[].
    const int c = tid;
    float a = 0.f;
    int curp = pid[0];
#pragma unroll
    for (int h = 0; h < 2; ++h) {
        float mv[16];
#pragma unroll
        for (int jj = 0; jj < 16; ++jj)
            mv[jj] = messages[(size_t)el[h * 16 + jj] * EMBED + c];
#pragma unroll
        for (int jj = 0; jj < 16; ++jj) {
            const int j  = h * 16 + jj;
            const int pj = pid[j];
            if (pj != curp) {               // wave-uniform branch
                atomicAdd(&sumf[(size_t)curp * EMBED + c], a);
                a = 0.f;
                curp = pj;
            }
            a = fmaf(mv[jj], P[j * PSTR + c], a);
        }
    }
    atomicAdd(&sumf[(size_t)curp * EMBED + c], a);
}

// f32 summed -> bf16 for the GEMM A operand
__global__ __launch_bounds__(256) void cvt_summed(
    const float* __restrict__ sf, __hip_bfloat16* __restrict__ sb)
{
    const size_t i = ((size_t)blockIdx.x * 256 + threadIdx.x) * 8;
    const float4v a = *(const float4v*)(sf + i);
    const float4v b = *(const float4v*)(sf + i + 4);
    short8 v;
#pragma unroll
    for (int r = 0; r < 4; ++r) { v[r] = bfbits(a[r]); v[4 + r] = bfbits(b[r]); }
    *(short8*)((short*)sb + i) = v;
}

// ---------------------------------------------------------------------------
// Weight transpose+convert, all three weights in one launch (z = which).
// Wt[n][k] = bf16(W[k][n]).
// ---------------------------------------------------------------------------
__global__ __launch_bounds__(256) void transpose_cvt_all(
    const float* __restrict__ W_up, const float* __restrict__ W_d0,
    const float* __restrict__ W_d1, __hip_bfloat16* __restrict__ wt_up,
    __hip_bfloat16* __restrict__ wt_d0, __hip_bfloat16* __restrict__ wt_d1)
{
    const int z = blockIdx.z;
    const float* W = (z == 0) ? W_up : (z == 1) ? W_d0 : W_d1;
    __hip_bfloat16* Wt = (z == 0) ? wt_up : (z == 1) ? wt_d0 : wt_d1;
    const int K = (z == 0) ? EMBED : OUTE;
    const int N = OUTE;
    if (blockIdx.y * 32 >= K) return;

    __shared__ float t[32][33];
    const int bn = blockIdx.x * 32;
    const int bk = blockIdx.y * 32;
    const int x = threadIdx.x & 31;
    const int y8 = threadIdx.x >> 5;
#pragma unroll
    for (int yy = y8; yy < 32; yy += 8)
        t[yy][x] = W[(size_t)(bk + yy) * N + bn + x];
    __syncthreads();
#pragma unroll
    for (int yy = y8; yy < 32; yy += 8)
        Wt[(size_t)(bn + yy) * K + bk + x] = __float2bfloat16(t[x][yy]);
}

// ---------------------------------------------------------------------------
// bf16 MFMA GEMM: 128x128 tile, BK=32, 4 waves, 4x4 mfma_f32_16x16x32_bf16
// per wave. FUSE=1: don't store C; instead out[row] += swish(v) * Wf[col]
// (shfl-reduce over the 16-lane row group, one fp32 atomicAdd per row).
// ---------------------------------------------------------------------------
#define BM 128
#define BN 128
#define BK 32
#define LDSP 40

template <int ACT, int FUSE>
__global__ __launch_bounds__(256) void gemm_mfma(
    const __hip_bfloat16* __restrict__ A,   // [M][K]
    const __hip_bfloat16* __restrict__ Bt,  // [N][K]
    const float* __restrict__ bias,          // [N] or null
    __hip_bfloat16* __restrict__ C,          // [M][N]   (FUSE=0)
    const float* __restrict__ Wf,            // [N]      (FUSE=1)
    float* __restrict__ out,                 // [M]      (FUSE=1)
    int M, int K, int N)
{
    __shared__ short As[BM * LDSP];
    __shared__ short Bs[BN * LDSP];

    const int tid  = threadIdx.x;
    const int bm   = blockIdx.x * BM;
    const int bn   = blockIdx.y * BN;
    const int wave = tid >> 6;
    const int lane = tid & 63;
    const int wm   = (wave >> 1) * 64;
    const int wn   = (wave & 1) * 64;
    const int l16  = lane & 15;
    const int quad = lane >> 4;

    float4v acc[4][4];
#pragma unroll
    for (int i = 0; i < 4; ++i)
#pragma unroll
        for (int j = 0; j < 4; ++j)
#pragma unroll
            for (int r = 0; r < 4; ++r) acc[i][j][r] = 0.f;

    const int sr = tid >> 1;         // staging row 0..127
    const int sh = (tid & 1) * 16;   // staging k-offset 0 / 16

    for (int k0 = 0; k0 < K; k0 += BK) {
        short8 av0, av1;
        if (bm + sr < M) {
            const short8* ga = (const short8*)((const short*)A + (size_t)(bm + sr) * K + k0 + sh);
            av0 = ga[0];
            av1 = ga[1];
        } else {
#pragma unroll
            for (int i = 0; i < 8; ++i) { av0[i] = 0; av1[i] = 0; }
        }
        *(short8*)&As[sr * LDSP + sh]     = av0;
        *(short8*)&As[sr * LDSP + sh + 8] = av1;
        const short8* gb = (const short8*)((const short*)Bt + (size_t)(bn + sr) * K + k0 + sh);
        short8 bv0 = gb[0], bv1 = gb[1];
        *(short8*)&Bs[sr * LDSP + sh]     = bv0;
        *(short8*)&Bs[sr * LDSP + sh + 8] = bv1;
        __syncthreads();

        short8 af[4], bf[4];
#pragma unroll
        for (int mt = 0; mt < 4; ++mt)
            af[mt] = *(const short8*)&As[(wm + mt * 16 + l16) * LDSP + quad * 8];
#pragma unroll
        for (int nt = 0; nt < 4; ++nt)
            bf[nt] = *(const short8*)&Bs[(wn + nt * 16 + l16) * LDSP + quad * 8];
#pragma unroll
        for (int mt = 0; mt < 4; ++mt)
#pragma unroll
            for (int nt = 0; nt < 4; ++nt)
                acc[mt][nt] = __builtin_amdgcn_mfma_f32_16x16x32_bf16(
                    af[mt], bf[nt], acc[mt][nt], 0, 0, 0);
        __syncthreads();
    }

    if (!FUSE) {
#pragma unroll
        for (int mt = 0; mt < 4; ++mt) {
            const int row0 = bm + wm + mt * 16 + quad * 4;
#pragma unroll
            for (int nt = 0; nt < 4; ++nt) {
                const int col = bn + wn + nt * 16 + l16;
                const float bv = bias ? bias[col] : 0.f;
#pragma unroll
                for (int r = 0; r < 4; ++r) {
                    const int rr = row0 + r;
                    if (rr < M) {
                        float v = acc[mt][nt][r] + bv;
                        if (ACT == 1) v = v / (1.f + expf(-v));
                        C[(size_t)rr * N + col] = __float2bfloat16(v);
                    }
                }
            }
        }
    } else {
        float bv[4], wfv[4];
#pragma unroll
        for (int nt = 0; nt < 4; ++nt) {
            const int col = bn + wn + nt * 16 + l16;
            bv[nt]  = bias ? bias[col] : 0.f;
            wfv[nt] = Wf[col];
        }
#pragma unroll
        for (int mt = 0; mt < 4; ++mt) {
#pragma unroll
            for (int r = 0; r < 4; ++r) {
                const int row = bm + wm + mt * 16 + quad * 4 + r;
                float s = 0.f;
#pragma unroll
                for (int nt = 0; nt < 4; ++nt) {
                    float v = acc[mt][nt][r] + bv[nt];
                    if (ACT == 1) v = v / (1.f + expf(-v));
                    s = fmaf(v, wfv[nt], s);
                }
#pragma unroll
                for (int o = 8; o > 0; o >>= 1) s += __shfl_down(s, o);
                if (l16 == 0 && row < M) atomicAdd(&out[row], s);
            }
        }
    }
}

extern "C" void kernel_launch(void* const* d_in, const int* in_sizes, int n_in,
                              void* d_out, int out_size, void* d_ws, size_t ws_size,
                              hipStream_t stream) {
    const float* messages = (const float*)d_in[0];
    const float* rbf      = (const float*)d_in[1];
    const int*   idx_i    = (const int*)d_in[2];
    const float* W_rbf    = (const float*)d_in[3];
    const float* W_up     = (const float*)d_in[4];
    const float* W_d0     = (const float*)d_in[5];
    const float* b_d0     = (const float*)d_in[6];
    const float* W_d1     = (const float*)d_in[7];
    const float* b_d1     = (const float*)d_in[8];
    const float* W_final  = (const float*)d_in[9];
    float* out = (float*)d_out;

    char* ws = (char*)d_ws;
    __hip_bfloat16* summed = (__hip_bfloat16*)(ws + WS_SUMMED);
    __hip_bfloat16* buf0   = (__hip_bfloat16*)(ws + WS_BUF0);
    __hip_bfloat16* buf1   = (__hip_bfloat16*)(ws + WS_BUF1);
    __hip_bfloat16* wt_up  = (__hip_bfloat16*)(ws + WS_WTUP);
    __hip_bfloat16* wt_d0  = (__hip_bfloat16*)(ws + WS_WTD0);
    __hip_bfloat16* wt_d1  = (__hip_bfloat16*)(ws + WS_WTD1);
    __hip_bfloat16* wrt    = (__hip_bfloat16*)(ws + WS_WRT);
    float* sumf = (float*)(ws + WS_SUMF);
    int* cnt   = (int*)(ws + WS_CNT);
    int* cur   = (int*)(ws + WS_CUR);
    int* offp  = (int*)(ws + WS_OFF);
    int* elist = (int*)(ws + WS_ELIST);

    hipMemsetAsync(ws + WS_CNT, 0, 80000, stream);                 // cnt+cur
    hipMemsetAsync(ws + WS_SUMF, 0, (size_t)N_PART * EMBED * 4, stream);
    hipMemsetAsync(d_out, 0, (size_t)N_PART * sizeof(float), stream);

    // CSR build
    hist_kernel<<<(N_EDGES_C + 255) / 256, 256, 0, stream>>>(idx_i, cnt);
    scan_kernel<<<1, 1024, 0, stream>>>(cnt, offp);
    fill_kernel<<<(N_EDGES_C + 255) / 256, 256, 0, stream>>>(idx_i, offp, cur, elist);

    // weight prep
    transpose_cvt_all<<<dim3(OUTE / 32, OUTE / 32, 3), 256, 0, stream>>>(
        W_up, W_d0, W_d1, wt_up, wt_d0, wt_d1);
    prep_wrbf<<<1, 256, 0, stream>>>(W_rbf, wrt);

    // gather with MFMA gate -> f32 summed -> bf16
    gather_mfma<<<N_EDGES_C / CHUNK, 256, 0, stream>>>(messages, rbf, idx_i,
                                                       elist, wrt, sumf);
    cvt_summed<<<(N_PART * EMBED) / (256 * 8), 256, 0, stream>>>(sumf, summed);

    // MLP via bf16 MFMA GEMMs; layer 3 fuses the W_final dot
    dim3 g((N_PART + BM - 1) / BM, OUTE / BN);  // 79 x 4
    gemm_mfma<0, 0><<<g, 256, 0, stream>>>(summed, wt_up, nullptr, buf0,
                                           nullptr, nullptr, N_PART, EMBED, OUTE);
    gemm_mfma<1, 0><<<g, 256, 0, stream>>>(buf0, wt_d0, b_d0, buf1,
                                           nullptr, nullptr, N_PART, OUTE, OUTE);
    gemm_mfma<1, 1><<<g, 256, 0, stream>>>(buf1, wt_d1, b_d1, nullptr,
                                           W_final, out, N_PART, OUTE, OUTE);
}

// Round 3
// 597.727 us; speedup vs baseline: 1.0888x; 1.0512x over previous
//
#include <hip/hip_runtime.h>
#include <hip/hip_bf16.h>
#include <math.h>

#define N_EDGES_C 320000
#define N_PART 10000
#define EMBED 256
#define NRBF 16
#define OUTE 512

typedef __attribute__((ext_vector_type(8))) short short8;
typedef __attribute__((ext_vector_type(4))) short short4v;
typedef __attribute__((ext_vector_type(4))) float float4v;

__device__ __forceinline__ short bfbits(float x) {
    __hip_bfloat16 h = __float2bfloat16(x);
    return *(short*)&h;
}

// ---------------- workspace layout (bytes; all 16-aligned) ----------------
// sumf and cnt are adjacent so ONE memset zeroes both.
#define WS_SUMF     0            // 10000*256*4 = 10,240,000  f32 scatter target
#define WS_CNT      10240000     // 10000*4
#define WS_OFF      10280000     // 10000*4
#define WS_EPOS     10320000     // 320000*4  (edge rank within its particle)
#define WS_ELIST    11600000     // 320000*4
#define WS_BUF0     12880000     // 10000*512*2 = 10,240,000  bf16
#define WS_BUF1     23120000     // 10,240,000
#define WS_WTUP     33360000     // 512*256*2 = 262,144       bf16 [N][K]
#define WS_WTD0     33630000     // 512*512*2 = 524,288
#define WS_WTD1     34160000     // 524,288
#define WS_WRT      34690000     // 256*64*2 = 32,768  (W_rbf^T hi/lo packed, K=64)

// ---------------------------------------------------------------------------
// CSR build: hist (saves per-edge rank -> fill is atomic-free) -> scan -> fill
// ---------------------------------------------------------------------------
__global__ __launch_bounds__(256) void hist_kernel(
    const int* __restrict__ idx_i, int* __restrict__ cnt, int* __restrict__ epos)
{
    int e = blockIdx.x * 256 + threadIdx.x;
    if (e < N_EDGES_C) epos[e] = atomicAdd(&cnt[idx_i[e]], 1);
}

__global__ __launch_bounds__(1024) void scan_kernel(
    const int* __restrict__ cnt, int* __restrict__ off)
{
    __shared__ int s[1024];
    const int t = threadIdx.x;
    const int base = t * 10;                 // 1024*10 >= 10000
    int v[10];
    int loc = 0;
#pragma unroll
    for (int i = 0; i < 10; ++i) {
        int idx = base + i;
        int c = (idx < N_PART) ? cnt[idx] : 0;
        v[i] = c;
        loc += c;
    }
    s[t] = loc;
    __syncthreads();
    for (int d = 1; d < 1024; d <<= 1) {
        int x = (t >= d) ? s[t - d] : 0;
        __syncthreads();
        s[t] += x;
        __syncthreads();
    }
    int pre = (t > 0) ? s[t - 1] : 0;        // exclusive prefix of thread sums
#pragma unroll
    for (int i = 0; i < 10; ++i) {
        int idx = base + i;
        if (idx < N_PART) off[idx] = pre;
        pre += v[i];
    }
}

__global__ __launch_bounds__(256) void fill_kernel(
    const int* __restrict__ idx_i, const int* __restrict__ off,
    const int* __restrict__ epos, int* __restrict__ elist)
{
    int e = blockIdx.x * 256 + threadIdx.x;
    if (e >= N_EDGES_C) return;
    elist[off[idx_i[e]] + epos[e]] = e;
}

// ---------------------------------------------------------------------------
// Weight transpose+convert; z = 0..2 are the MLP weights, z == 3 packs
// W_rbf^T into wrt[n][k] bf16 [256][64]:
//   k  0..15 : hi(W_rbf[k][n]),  k 16..31 : hi,  k 32..47 : lo,  k 48..63 : 0
// With A = [x_hi | x_lo | x_hi | 0] the MFMA computes
//   x_hi*w_hi + x_lo*w_hi + x_hi*w_lo = x*w - x_lo*w_lo (error ~1e-5).
// ---------------------------------------------------------------------------
__global__ __launch_bounds__(256) void transpose_cvt_all(
    const float* __restrict__ W_up, const float* __restrict__ W_d0,
    const float* __restrict__ W_d1, const float* __restrict__ W_rbf,
    __hip_bfloat16* __restrict__ wt_up, __hip_bfloat16* __restrict__ wt_d0,
    __hip_bfloat16* __restrict__ wt_d1, __hip_bfloat16* __restrict__ wrt)
{
    const int z = blockIdx.z;
    if (z == 3) {
        if (blockIdx.x != 0 || blockIdx.y != 0) return;
        const int n = threadIdx.x;
        short row[64];
#pragma unroll
        for (int k = 0; k < 16; ++k) {
            const float w = W_rbf[k * EMBED + n];
            const short h = bfbits(w);
            __hip_bfloat16 hb = *(__hip_bfloat16*)&h;
            const short l = bfbits(w - __bfloat162float(hb));
            row[k] = h; row[16 + k] = h; row[32 + k] = l; row[48 + k] = 0;
        }
        short* dst = (short*)wrt + n * 64;
#pragma unroll
        for (int g = 0; g < 8; ++g) {
            short8 v;
#pragma unroll
            for (int i = 0; i < 8; ++i) v[i] = row[g * 8 + i];
            *(short8*)(dst + g * 8) = v;
        }
        return;
    }
    const float* W = (z == 0) ? W_up : (z == 1) ? W_d0 : W_d1;
    __hip_bfloat16* Wt = (z == 0) ? wt_up : (z == 1) ? wt_d0 : wt_d1;
    const int K = (z == 0) ? EMBED : OUTE;
    const int N = OUTE;
    if (blockIdx.y * 32 >= K) return;

    __shared__ float t[32][33];
    const int bn = blockIdx.x * 32;
    const int bk = blockIdx.y * 32;
    const int x = threadIdx.x & 31;
    const int y8 = threadIdx.x >> 5;
#pragma unroll
    for (int yy = y8; yy < 32; yy += 8)
        t[yy][x] = W[(size_t)(bk + yy) * N + bn + x];
    __syncthreads();
#pragma unroll
    for (int yy = y8; yy < 32; yy += 8)
        Wt[(size_t)(bn + yy) * K + bk + x] = __float2bfloat16(t[x][yy]);
}

// ---------------------------------------------------------------------------
// Gather (MFMA gate): one block per 32-edge CSR chunk.
//   phase 0: el/pid into LDS
//   phase 1: rbf rows -> bf16 hi/lo A-tile [32][64] in LDS;
//            P[32][256] = A @ wrt via 16 mfma_f32_16x16x32_bf16 per wave
//   phase 2: thread-per-column; acc += messages[e][c]*P[j][c] over the chunk,
//            flushing to f32 summed at particle-run boundaries (CSR order
//            makes runs contiguous; boundary particles handled by atomicAdd).
// LDS = 4.6K(A) + 33.3K(P) + 0.25K = 38.1 KB -> 4 blocks/CU.
// Bound by the 327 MB messages stream (~55-70 us at HBM rate).
// ---------------------------------------------------------------------------
#define CHUNK 32
#define ASTR 72          // A LDS stride in shorts (64 + 8 pad)
#define PSTR 260         // P LDS stride in floats

__global__ __launch_bounds__(256) void gather_mfma(
    const float* __restrict__ messages, const float* __restrict__ rbf,
    const int* __restrict__ idx_i, const int* __restrict__ elist,
    const __hip_bfloat16* __restrict__ wrt,
    float* __restrict__ sumf)
{
    __shared__ short A[CHUNK * ASTR];
    __shared__ float P[CHUNK * PSTR];
    __shared__ int el[CHUNK];
    __shared__ int pid[CHUNK];

    const int tid  = threadIdx.x;
    const int wave = tid >> 6;
    const int lane = tid & 63;
    const int l16  = lane & 15;
    const int quad = lane >> 4;
    const int base = blockIdx.x * CHUNK;   // 320000/32 = 10000 chunks exactly

    // b-frags from global wrt (32 KB, L2-hot): wave w owns n-tiles 4w..4w+3.
    short8 bfr[4][2];
#pragma unroll
    for (int i = 0; i < 4; ++i) {
        const int col = (wave * 4 + i) * 16 + l16;
#pragma unroll
        for (int s = 0; s < 2; ++s)
            bfr[i][s] = *(const short8*)((const short*)wrt + col * 64 + s * 32 + quad * 8);
    }

    if (tid < CHUNK) {
        const int e = elist[base + tid];
        el[tid] = e;
        pid[tid] = idx_i[e];
    }
    __syncthreads();

    // A staging: threads 0..127; j = t>>2, k-quad = (t&3)*4
    if (tid < 128) {
        const int j  = tid >> 2;
        const int kq = (tid & 3) << 2;
        const float4v r = *(const float4v*)(rbf + (size_t)el[j] * NRBF + kq);
        short4v hi, lo;
#pragma unroll
        for (int i = 0; i < 4; ++i) {
            const short h = bfbits(r[i]);
            __hip_bfloat16 hb = *(__hip_bfloat16*)&h;
            hi[i] = h;
            lo[i] = bfbits(r[i] - __bfloat162float(hb));
        }
        *(short4v*)&A[j * ASTR + kq]      = hi;
        *(short4v*)&A[j * ASTR + 16 + kq] = lo;
        *(short4v*)&A[j * ASTR + 32 + kq] = hi;
        *(short4v*)&A[j * ASTR + 48 + kq] = (short4v){0, 0, 0, 0};
    }
    __syncthreads();

    // MFMA: 2 m-tiles x 4 n-tiles x 2 k-steps per wave
    float4v acc[2][4];
#pragma unroll
    for (int mt = 0; mt < 2; ++mt)
#pragma unroll
        for (int i = 0; i < 4; ++i)
#pragma unroll
            for (int r = 0; r < 4; ++r) acc[mt][i][r] = 0.f;

    short8 af[2][2];
#pragma unroll
    for (int mt = 0; mt < 2; ++mt)
#pragma unroll
        for (int s = 0; s < 2; ++s)
            af[mt][s] = *(const short8*)&A[(mt * 16 + l16) * ASTR + s * 32 + quad * 8];
#pragma unroll
    for (int mt = 0; mt < 2; ++mt)
#pragma unroll
        for (int i = 0; i < 4; ++i) {
            acc[mt][i] = __builtin_amdgcn_mfma_f32_16x16x32_bf16(af[mt][0], bfr[i][0], acc[mt][i], 0, 0, 0);
            acc[mt][i] = __builtin_amdgcn_mfma_f32_16x16x32_bf16(af[mt][1], bfr[i][1], acc[mt][i], 0, 0, 0);
        }
    // C layout (verified m89): col = lane&15, row = (lane>>4)*4 + r
#pragma unroll
    for (int mt = 0; mt < 2; ++mt)
#pragma unroll
        for (int i = 0; i < 4; ++i) {
            const int col  = (wave * 4 + i) * 16 + l16;
            const int row0 = mt * 16 + quad * 4;
#pragma unroll
            for (int r = 0; r < 4; ++r)
                P[(row0 + r) * PSTR + col] = acc[mt][i][r];
        }
    __syncthreads();

    // phase 2: thread c = tid; two half-chunks of 16 to bound VGPR for mv[].
    const int c = tid;
    float a = 0.f;
    int curp = pid[0];
#pragma unroll
    for (int h = 0; h < 2; ++h) {
        float mv[16];
#pragma unroll
        for (int jj = 0; jj < 16; ++jj)
            mv[jj] = messages[(size_t)el[h * 16 + jj] * EMBED + c];
#pragma unroll
        for (int jj = 0; jj < 16; ++jj) {
            const int j  = h * 16 + jj;
            const int pj = pid[j];
            if (pj != curp) {               // wave-uniform branch
                atomicAdd(&sumf[(size_t)curp * EMBED + c], a);
                a = 0.f;
                curp = pj;
            }
            a = fmaf(mv[jj], P[j * PSTR + c], a);
        }
    }
    atomicAdd(&sumf[(size_t)curp * EMBED + c], a);
}

// ---------------------------------------------------------------------------
// bf16 MFMA GEMM: 128x128 tile, BK=32, 4 waves, 4x4 mfma_f32_16x16x32_bf16
// per wave. AF32=1: A operand is f32 (sumf), converted to bf16 during LDS
// staging (fuses the old cvt_summed pass; identical rounding).
// FUSE=1: don't store C; out[row] += swish(v) * Wf[col] via shfl-reduce +
// one fp32 atomicAdd per row.
// ---------------------------------------------------------------------------
#define BM 128
#define BN 128
#define BK 32
#define LDSP 40

template <int ACT, int FUSE, int AF32>
__global__ __launch_bounds__(256) void gemm_mfma(
    const __hip_bfloat16* __restrict__ A,   // [M][K] bf16 (AF32=0)
    const float* __restrict__ Af,            // [M][K] f32  (AF32=1)
    const __hip_bfloat16* __restrict__ Bt,  // [N][K]
    const float* __restrict__ bias,          // [N] or null
    __hip_bfloat16* __restrict__ C,          // [M][N]   (FUSE=0)
    const float* __restrict__ Wf,            // [N]      (FUSE=1)
    float* __restrict__ out,                 // [M]      (FUSE=1)
    int M, int K, int N)
{
    __shared__ short As[BM * LDSP];
    __shared__ short Bs[BN * LDSP];

    const int tid  = threadIdx.x;
    const int bm   = blockIdx.x * BM;
    const int bn   = blockIdx.y * BN;
    const int wave = tid >> 6;
    const int lane = tid & 63;
    const int wm   = (wave >> 1) * 64;
    const int wn   = (wave & 1) * 64;
    const int l16  = lane & 15;
    const int quad = lane >> 4;

    float4v acc[4][4];
#pragma unroll
    for (int i = 0; i < 4; ++i)
#pragma unroll
        for (int j = 0; j < 4; ++j)
#pragma unroll
            for (int r = 0; r < 4; ++r) acc[i][j][r] = 0.f;

    const int sr = tid >> 1;         // staging row 0..127
    const int sh = (tid & 1) * 16;   // staging k-offset 0 / 16

    for (int k0 = 0; k0 < K; k0 += BK) {
        short8 av0, av1;
        if (bm + sr < M) {
            if (AF32) {
                const float4v* ga = (const float4v*)(Af + (size_t)(bm + sr) * K + k0 + sh);
                const float4v f0 = ga[0], f1 = ga[1], f2 = ga[2], f3 = ga[3];
#pragma unroll
                for (int r = 0; r < 4; ++r) {
                    av0[r]     = bfbits(f0[r]);
                    av0[4 + r] = bfbits(f1[r]);
                    av1[r]     = bfbits(f2[r]);
                    av1[4 + r] = bfbits(f3[r]);
                }
            } else {
                const short8* ga = (const short8*)((const short*)A + (size_t)(bm + sr) * K + k0 + sh);
                av0 = ga[0];
                av1 = ga[1];
            }
        } else {
#pragma unroll
            for (int i = 0; i < 8; ++i) { av0[i] = 0; av1[i] = 0; }
        }
        *(short8*)&As[sr * LDSP + sh]     = av0;
        *(short8*)&As[sr * LDSP + sh + 8] = av1;
        const short8* gb = (const short8*)((const short*)Bt + (size_t)(bn + sr) * K + k0 + sh);
        short8 bv0 = gb[0], bv1 = gb[1];
        *(short8*)&Bs[sr * LDSP + sh]     = bv0;
        *(short8*)&Bs[sr * LDSP + sh + 8] = bv1;
        __syncthreads();

        short8 af[4], bf[4];
#pragma unroll
        for (int mt = 0; mt < 4; ++mt)
            af[mt] = *(const short8*)&As[(wm + mt * 16 + l16) * LDSP + quad * 8];
#pragma unroll
        for (int nt = 0; nt < 4; ++nt)
            bf[nt] = *(const short8*)&Bs[(wn + nt * 16 + l16) * LDSP + quad * 8];
#pragma unroll
        for (int mt = 0; mt < 4; ++mt)
#pragma unroll
            for (int nt = 0; nt < 4; ++nt)
                acc[mt][nt] = __builtin_amdgcn_mfma_f32_16x16x32_bf16(
                    af[mt], bf[nt], acc[mt][nt], 0, 0, 0);
        __syncthreads();
    }

    if (!FUSE) {
#pragma unroll
        for (int mt = 0; mt < 4; ++mt) {
            const int row0 = bm + wm + mt * 16 + quad * 4;
#pragma unroll
            for (int nt = 0; nt < 4; ++nt) {
                const int col = bn + wn + nt * 16 + l16;
                const float bv = bias ? bias[col] : 0.f;
#pragma unroll
                for (int r = 0; r < 4; ++r) {
                    const int rr = row0 + r;
                    if (rr < M) {
                        float v = acc[mt][nt][r] + bv;
                        if (ACT == 1) v = v / (1.f + expf(-v));
                        C[(size_t)rr * N + col] = __float2bfloat16(v);
                    }
                }
            }
        }
    } else {
        float bv[4], wfv[4];
#pragma unroll
        for (int nt = 0; nt < 4; ++nt) {
            const int col = bn + wn + nt * 16 + l16;
            bv[nt]  = bias ? bias[col] : 0.f;
            wfv[nt] = Wf[col];
        }
#pragma unroll
        for (int mt = 0; mt < 4; ++mt) {
#pragma unroll
            for (int r = 0; r < 4; ++r) {
                const int row = bm + wm + mt * 16 + quad * 4 + r;
                float s = 0.f;
#pragma unroll
                for (int nt = 0; nt < 4; ++nt) {
                    float v = acc[mt][nt][r] + bv[nt];
                    if (ACT == 1) v = v / (1.f + expf(-v));
                    s = fmaf(v, wfv[nt], s);
                }
#pragma unroll
                for (int o = 8; o > 0; o >>= 1) s += __shfl_down(s, o);
                if (l16 == 0 && row < M) atomicAdd(&out[row], s);
            }
        }
    }
}

extern "C" void kernel_launch(void* const* d_in, const int* in_sizes, int n_in,
                              void* d_out, int out_size, void* d_ws, size_t ws_size,
                              hipStream_t stream) {
    const float* messages = (const float*)d_in[0];
    const float* rbf      = (const float*)d_in[1];
    const int*   idx_i    = (const int*)d_in[2];
    const float* W_rbf    = (const float*)d_in[3];
    const float* W_up     = (const float*)d_in[4];
    const float* W_d0     = (const float*)d_in[5];
    const float* b_d0     = (const float*)d_in[6];
    const float* W_d1     = (const float*)d_in[7];
    const float* b_d1     = (const float*)d_in[8];
    const float* W_final  = (const float*)d_in[9];
    float* out = (float*)d_out;

    char* ws = (char*)d_ws;
    float* sumf = (float*)(ws + WS_SUMF);
    int* cnt   = (int*)(ws + WS_CNT);
    int* offp  = (int*)(ws + WS_OFF);
    int* epos  = (int*)(ws + WS_EPOS);
    int* elist = (int*)(ws + WS_ELIST);
    __hip_bfloat16* buf0   = (__hip_bfloat16*)(ws + WS_BUF0);
    __hip_bfloat16* buf1   = (__hip_bfloat16*)(ws + WS_BUF1);
    __hip_bfloat16* wt_up  = (__hip_bfloat16*)(ws + WS_WTUP);
    __hip_bfloat16* wt_d0  = (__hip_bfloat16*)(ws + WS_WTD0);
    __hip_bfloat16* wt_d1  = (__hip_bfloat16*)(ws + WS_WTD1);
    __hip_bfloat16* wrt    = (__hip_bfloat16*)(ws + WS_WRT);

    // sumf + cnt are contiguous: one fill zeroes both.
    hipMemsetAsync(ws + WS_SUMF, 0, 10280000, stream);
    hipMemsetAsync(d_out, 0, (size_t)N_PART * sizeof(float), stream);

    // CSR build (fill is atomic-free: hist saved each edge's rank)
    hist_kernel<<<(N_EDGES_C + 255) / 256, 256, 0, stream>>>(idx_i, cnt, epos);
    scan_kernel<<<1, 1024, 0, stream>>>(cnt, offp);
    fill_kernel<<<(N_EDGES_C + 255) / 256, 256, 0, stream>>>(idx_i, offp, epos, elist);

    // weight prep: 3 transposes + W_rbf hi/lo pack in one launch
    transpose_cvt_all<<<dim3(OUTE / 32, OUTE / 32, 4), 256, 0, stream>>>(
        W_up, W_d0, W_d1, W_rbf, wt_up, wt_d0, wt_d1, wrt);

    // gather with MFMA gate -> f32 sumf
    gather_mfma<<<N_EDGES_C / CHUNK, 256, 0, stream>>>(messages, rbf, idx_i,
                                                       elist, wrt, sumf);

    // MLP via bf16 MFMA GEMMs; GEMM1 converts f32 sumf in staging;
    // layer 3 fuses the W_final dot.
    dim3 g((N_PART + BM - 1) / BM, OUTE / BN);  // 79 x 4
    gemm_mfma<0, 0, 1><<<g, 256, 0, stream>>>(nullptr, sumf, wt_up, nullptr, buf0,
                                              nullptr, nullptr, N_PART, EMBED, OUTE);
    gemm_mfma<1, 0, 0><<<g, 256, 0, stream>>>(buf0, nullptr, wt_d0, b_d0, buf1,
                                              nullptr, nullptr, N_PART, OUTE, OUTE);
    gemm_mfma<1, 1, 0><<<g, 256, 0, stream>>>(buf1, nullptr, wt_d1, b_d1, nullptr,
                                              W_final, out, N_PART, OUTE, OUTE);
}